// Round 4
// baseline (222.324 us; speedup 1.0000x reference)
//
#include <hip/hip_runtime.h>

// NovelKQRAttention — algebraically collapsed + single persistent kernel.
// energy = a[...,q,None] + b[...,None,k]; softmax over k => a cancels,
// attn = softmax_k(b) independent of q => deform-conv path dead,
// attention output constant over spatial dims.
//
// One kernel, 512 blocks x 256 threads, 4 device-scope grid barriers:
//   P1 bpart : partial b over 36-ch chunk (kb recomputed per block)
//   P2 softmax: blocks 0..17 sum 16 chunks + softmax -> p
//   P3 wx    : wx[n,h,c] = sum_k p[n,h,k]*x_kv[n,c,k]  (p staged in LDS)
//   P4 ov    : ov[n,o] = value_w[o,:].wx[n,h(o),:]   (1 wave/output)
//   P5 po+final: po[n,o]=proj_w[o,:].ov[n,:]+proj_b; out row = g*po + x row
// Barrier counters in ws[0..15] (floats), zeroed by hipMemsetAsync each call.

#define CCH 576
#define NH 9
#define HW 4096   // 64*64
#define KHW 1024  // 32*32
#define W 64
#define NBLK 512
#define CHN 16    // channel chunks
#define CPC 36    // channels per chunk

// ws float offsets
#define WS_BPART 16                      // 2*16*9*1024 = 294912
#define WS_P     (16 + 294912)           // 2*9*1024    = 18432
#define WS_WX    (16 + 294912 + 18432)   // 2*9*576     = 10368
#define WS_OV    (16 + 294912 + 18432 + 10368)  // 2*576 = 1152

__device__ __forceinline__ void gridbar(unsigned* cnt, unsigned target) {
    __syncthreads();
    if (threadIdx.x == 0) {
        __threadfence();  // publish prior global writes device-wide
        __hip_atomic_fetch_add(cnt, 1u, __ATOMIC_ACQ_REL, __HIP_MEMORY_SCOPE_AGENT);
        while (__hip_atomic_load(cnt, __ATOMIC_ACQUIRE, __HIP_MEMORY_SCOPE_AGENT) < target)
            __builtin_amdgcn_s_sleep(8);
        __threadfence();
    }
    __syncthreads();
}

__global__ __launch_bounds__(256, 2) void k_fused(
    const float* __restrict__ x, const float* __restrict__ key_w,
    const float* __restrict__ value_w, const float* __restrict__ proj_w,
    const float* __restrict__ proj_b, const float* __restrict__ appr_bias,
    const float* __restrict__ gamma, float* __restrict__ out, float* __restrict__ ws)
{
    __shared__ float smem[NH * KHW];   // 36 KB, reused across phases
    __shared__ float redm[4], reds[4];
    unsigned* bars = (unsigned*)ws;
    float* bpart = ws + WS_BPART;
    float* p     = ws + WS_P;
    float* wx    = ws + WS_WX;
    float* ov    = ws + WS_OV;

    const int b   = blockIdx.x;
    const int tid = threadIdx.x;
    const int wv  = tid >> 6, ln = tid & 63;

    // ---------------- P1: bpart ----------------
    {
        int kblk = b & 15, n = (b >> 4) & 1, ch = b >> 5;
        int c0 = ch * CPC, k0 = kblk * 64;
        float* ab   = smem;          // 576
        float* kbs  = smem + 576;    // 9*36 = 324   [h*CPC+cl]
        float* part = smem + 1024;   // 4*576 = 2304 [wv*576 + ln*9 + h]
        for (int i = tid; i < CCH; i += 256) ab[i] = appr_bias[i];
        __syncthreads();
        for (int t = tid; t < NH * CPC; t += 256) {
            int h = t / CPC, cl = t % CPC;
            float s = 0.f;
            #pragma unroll 8
            for (int e = 0; e < 64; ++e)
                s += ab[h * 64 + e] * key_w[(size_t)(h * 64 + e) * CCH + c0 + cl];
            kbs[t] = s;
        }
        __syncthreads();
        int k = k0 + ln;
        int ky = k >> 5, kx = k & 31;
        const float* xb = x + (size_t)n * CCH * HW + (size_t)(ky * 2) * W + kx * 2;
        float acc[NH];
        #pragma unroll
        for (int h = 0; h < NH; ++h) acc[h] = 0.f;
        for (int cl = wv; cl < CPC; cl += 4) {
            float xv = xb[(size_t)(c0 + cl) * HW];
            #pragma unroll
            for (int h = 0; h < NH; ++h) acc[h] += kbs[h * CPC + cl] * xv;
        }
        #pragma unroll
        for (int h = 0; h < NH; ++h) part[wv * 576 + ln * 9 + h] = acc[h];
        __syncthreads();
        for (int t = tid; t < 576; t += 256) {
            int l = t / 9, h = t % 9;
            float s = part[t] + part[576 + t] + part[1152 + t] + part[1728 + t];
            bpart[(((size_t)n * CHN + ch) * NH + h) * KHW + k0 + l] = s;
        }
    }
    gridbar(bars + 0, NBLK);

    // ---------------- P2: chunk-sum + softmax (blocks 0..17) ----------------
    if (b < 2 * NH) {
        int n = b / NH, h = b % NH;
        float s[4];
        #pragma unroll
        for (int j = 0; j < 4; ++j) {
            int k = tid + j * 256;
            float v = 0.f;
            #pragma unroll
            for (int ch = 0; ch < CHN; ++ch)
                v += bpart[(((size_t)n * CHN + ch) * NH + h) * KHW + k];
            s[j] = v;
        }
        float m = fmaxf(fmaxf(s[0], s[1]), fmaxf(s[2], s[3]));
        #pragma unroll
        for (int off = 32; off >= 1; off >>= 1) m = fmaxf(m, __shfl_xor(m, off, 64));
        if (ln == 0) redm[wv] = m;
        __syncthreads();
        m = fmaxf(fmaxf(redm[0], redm[1]), fmaxf(redm[2], redm[3]));
        float e[4], lsum = 0.f;
        #pragma unroll
        for (int j = 0; j < 4; ++j) { e[j] = __expf(s[j] - m); lsum += e[j]; }
        #pragma unroll
        for (int off = 32; off >= 1; off >>= 1) lsum += __shfl_xor(lsum, off, 64);
        if (ln == 0) reds[wv] = lsum;
        __syncthreads();
        float inv = 1.f / (reds[0] + reds[1] + reds[2] + reds[3]);
        #pragma unroll
        for (int j = 0; j < 4; ++j)
            p[(size_t)b * KHW + tid + j * 256] = e[j] * inv;
    }
    gridbar(bars + 1, NBLK);

    // ---------------- P3: wx ----------------
    {
        int n = b & 1;
        const float4* p4 = (const float4*)(p + (size_t)n * NH * KHW);
        float4* ps4 = (float4*)smem;
        for (int i = tid; i < NH * KHW / 4; i += 256) ps4[i] = p4[i];
        __syncthreads();
        int c = (b >> 1) * 4 + wv;   // 0..1023, active < 576
        if (c < CCH) {
            const float* xb = x + ((size_t)n * CCH + c) * HW;
            float acc[NH];
            #pragma unroll
            for (int h = 0; h < NH; ++h) acc[h] = 0.f;
            #pragma unroll 4
            for (int j = 0; j < 16; ++j) {
                int k = ln + 64 * j;
                int ky = k >> 5, kx = k & 31;
                float xv = xb[(size_t)(ky * 2) * W + kx * 2];
                #pragma unroll
                for (int h = 0; h < NH; ++h) acc[h] += smem[h * KHW + k] * xv;
            }
            #pragma unroll
            for (int h = 0; h < NH; ++h) {
                float v = acc[h];
                #pragma unroll
                for (int off = 32; off >= 1; off >>= 1) v += __shfl_xor(v, off, 64);
                if (ln == 0) wx[((size_t)n * NH + h) * CCH + c] = v;
            }
        }
    }
    gridbar(bars + 2, NBLK);

    // ---------------- P4: ov (1 wave per output) ----------------
    {
        int gw = b * 4 + wv;   // 0..2047
        if (gw < 2 * CCH) {
            int n = gw / CCH, o = gw % CCH, h = o >> 6;
            const float* vw  = value_w + (size_t)o * CCH;
            const float* wxr = wx + ((size_t)n * NH + h) * CCH;
            float acc = 0.f;
            #pragma unroll
            for (int j = 0; j < 9; ++j) acc += vw[ln + 64 * j] * wxr[ln + 64 * j];
            #pragma unroll
            for (int off = 32; off >= 1; off >>= 1) acc += __shfl_xor(acc, off, 64);
            if (ln == 0) ov[n * CCH + o] = acc;
        }
    }
    gridbar(bars + 3, NBLK);

    // ---------------- P5: po + final stream (1 wave per output row) ----------------
    {
        int gw = b * 4 + wv;
        if (gw < 2 * CCH) {
            int n = gw / CCH, o = gw % CCH;
            const float* pw  = proj_w + (size_t)o * CCH;
            const float* ovr = ov + n * CCH;
            float acc = 0.f;
            #pragma unroll
            for (int j = 0; j < 9; ++j) acc += pw[ln + 64 * j] * ovr[ln + 64 * j];
            #pragma unroll
            for (int off = 32; off >= 1; off >>= 1) acc += __shfl_xor(acc, off, 64);
            float base = gamma[0] * (acc + proj_b[o]);   // all lanes hold full sum
            const float4* x4 = (const float4*)(x + ((size_t)n * CCH + o) * HW);
            float4* o4 = (float4*)(out + ((size_t)n * CCH + o) * HW);
            #pragma unroll 4
            for (int j = 0; j < 16; ++j) {
                float4 v = x4[ln + 64 * j];
                v.x += base; v.y += base; v.z += base; v.w += base;
                o4[ln + 64 * j] = v;
            }
        }
    }
}

extern "C" void kernel_launch(void* const* d_in, const int* in_sizes, int n_in,
                              void* d_out, int out_size, void* d_ws, size_t ws_size,
                              hipStream_t stream) {
    const float* x         = (const float*)d_in[0];
    const float* key_w     = (const float*)d_in[1];
    // d_in[2] offset_w, d_in[3] dconv_w, d_in[8] appr_bias_q: dead path (a cancels in softmax)
    const float* value_w   = (const float*)d_in[4];
    const float* proj_w    = (const float*)d_in[5];
    const float* proj_b    = (const float*)d_in[6];
    const float* appr_bias = (const float*)d_in[7];
    const float* gamma     = (const float*)d_in[9];
    float* out = (float*)d_out;

    // zero the 4 barrier counters (first 64 B of ws) each call
    hipMemsetAsync(d_ws, 0, 64, stream);
    k_fused<<<NBLK, 256, 0, stream>>>(x, key_w, value_w, proj_w, proj_b,
                                      appr_bias, gamma, out, (float*)d_ws);
}

// Round 6
// 52.314 us; speedup vs baseline: 4.2498x; 4.2498x over previous
//
#include <hip/hip_runtime.h>

// NovelKQRAttention — algebraically collapsed, 4-kernel chain.
// energy = a[...,q,None] + b[...,None,k]; softmax over k => a cancels,
// attn = softmax_k(b) independent of q => deform-conv path is dead,
// attention output constant over spatial dims.
//
//   K1 k_bpart  : partial b[n,h,k] per 36-ch chunk (kb recomputed per block)
//   K2 k_swx    : chunk-sum + softmax (in LDS, per block) + wx reduction
//   K3 k_ov     : ov[n,o] = value_w[o,:] . wx[n,h(o),:]   (1 wave/output)
//   K4 k_pofinal: po = proj_w[o,:].ov + proj_b; out row = gamma*po + x row
//                 (1 block per (n,o) row)

#define CCH 576
#define NH 9
#define HW 4096   // 64*64
#define KHW 1024  // 32*32
#define W 64
#define CHN 16    // channel chunks
#define CPC 36    // channels per chunk

// ws float offsets
#define WS_BPART 0                   // 2*16*9*1024 = 294912
#define WS_WX    294912              // 2*9*576     = 10368
#define WS_OV    (294912 + 10368)    // 2*576       = 1152

// grid (4 kblk, 2 n, 16 chunk), block 256.
__global__ void k_bpart(const float* __restrict__ x, const float* __restrict__ key_w,
                        const float* __restrict__ appr_bias, float* __restrict__ bpart) {
    int k  = blockIdx.x * 256 + threadIdx.x;   // 0..1023
    int n  = blockIdx.y;
    int ch = blockIdx.z;
    int c0 = ch * CPC;

    __shared__ float ab[CCH];
    __shared__ float kbs[NH][CPC];
    for (int i = threadIdx.x; i < CCH; i += 256) ab[i] = appr_bias[i];
    __syncthreads();
    for (int t = threadIdx.x; t < NH * CPC; t += 256) {
        int h = t / CPC, cl = t % CPC;
        float s = 0.f;
        #pragma unroll 8
        for (int e = 0; e < 64; ++e)
            s += ab[h * 64 + e] * key_w[(size_t)(h * 64 + e) * CCH + c0 + cl];
        kbs[h][cl] = s;
    }
    __syncthreads();

    int ky = k >> 5, kx = k & 31;
    const float* xb = x + (size_t)n * CCH * HW + (size_t)(ky * 2) * W + kx * 2;
    float acc[NH];
    #pragma unroll
    for (int h = 0; h < NH; ++h) acc[h] = 0.f;
    for (int cl = 0; cl < CPC; ++cl) {
        float xv = xb[(size_t)(c0 + cl) * HW];
        #pragma unroll
        for (int h = 0; h < NH; ++h) acc[h] += kbs[h][cl] * xv;
    }
    #pragma unroll
    for (int h = 0; h < NH; ++h)
        bpart[(((size_t)n * CHN + ch) * NH + h) * KHW + k] = acc[h];
}

// grid (144 c-tiles, 2 n), block 256 (4 waves).
// Phase A: sum 16 bpart chunks into LDS b[9][1024] (coalesced, L2-served).
// Phase B: per-wave softmax of rows h = wv, wv+4, ... (disjoint rows).
// Phase C: wave wv handles channel c = bid.x*4+wv; wx[n,h,c] = sum_k p*x_kv.
__global__ void k_swx(const float* __restrict__ x, const float* __restrict__ bpart,
                      float* __restrict__ wx) {
    int n = blockIdx.y;
    int tid = threadIdx.x;
    int wv = tid >> 6, ln = tid & 63;
    __shared__ float sm[NH * KHW];   // 36 KB

    // A: chunk-sum
    const float* bp = bpart + (size_t)n * CHN * NH * KHW;
    for (int i = tid; i < NH * KHW; i += 256) {
        float v = 0.f;
        #pragma unroll
        for (int ch = 0; ch < CHN; ++ch)
            v += bp[(size_t)ch * NH * KHW + i];
        sm[i] = v;
    }
    __syncthreads();

    // B: softmax per head-row (waves own disjoint rows)
    for (int h = wv; h < NH; h += 4) {
        float* row = sm + h * KHW;
        float m = -1e30f;
        #pragma unroll
        for (int j = 0; j < 16; ++j) m = fmaxf(m, row[ln + 64 * j]);
        #pragma unroll
        for (int off = 32; off >= 1; off >>= 1) m = fmaxf(m, __shfl_xor(m, off, 64));
        float s = 0.f;
        #pragma unroll
        for (int j = 0; j < 16; ++j) {
            float e = __expf(row[ln + 64 * j] - m);
            row[ln + 64 * j] = e;
            s += e;
        }
        #pragma unroll
        for (int off = 32; off >= 1; off >>= 1) s += __shfl_xor(s, off, 64);
        float inv = 1.f / s;
        #pragma unroll
        for (int j = 0; j < 16; ++j) row[ln + 64 * j] *= inv;
    }
    __syncthreads();

    // C: wx reduction; c = bid.x*4+wv covers 0..575 exactly
    int c = blockIdx.x * 4 + wv;
    const float* xb = x + ((size_t)n * CCH + c) * HW;
    float acc[NH];
    #pragma unroll
    for (int h = 0; h < NH; ++h) acc[h] = 0.f;
    #pragma unroll 4
    for (int j = 0; j < 16; ++j) {
        int k = ln + 64 * j;
        int ky = k >> 5, kx = k & 31;
        float xv = xb[(size_t)(ky * 2) * W + kx * 2];
        #pragma unroll
        for (int h = 0; h < NH; ++h) acc[h] += sm[h * KHW + k] * xv;
    }
    #pragma unroll
    for (int h = 0; h < NH; ++h) {
        float v = acc[h];
        #pragma unroll
        for (int off = 32; off >= 1; off >>= 1) v += __shfl_xor(v, off, 64);
        if (ln == 0) wx[((size_t)n * NH + h) * CCH + c] = v;
    }
}

// one wave per output element; grid 288, block 256 (4 waves)
__global__ void k_ov(const float* __restrict__ value_w, const float* __restrict__ wx,
                     float* __restrict__ ov) {
    int g = blockIdx.x * 4 + (threadIdx.x >> 6);   // 0..1151
    int lane = threadIdx.x & 63;
    int n = g / CCH, o = g % CCH;
    int h = o >> 6;
    const float* vw  = value_w + (size_t)o * CCH;
    const float* wxr = wx + ((size_t)n * NH + h) * CCH;
    float acc = 0.f;
    #pragma unroll
    for (int j = 0; j < 9; ++j)
        acc += vw[lane + 64 * j] * wxr[lane + 64 * j];
    #pragma unroll
    for (int off = 32; off >= 1; off >>= 1)
        acc += __shfl_xor(acc, off, 64);
    if (lane == 0) ov[n * CCH + o] = acc;
}

// grid 1152 (= 2*576, one block per (n,o) row), block 256.
// Block-wide dot(proj_w[o,:], ov[n,:]) then stream out row = x row + base.
__global__ void k_pofinal(const float* __restrict__ proj_w, const float* __restrict__ proj_b,
                          const float* __restrict__ ov, const float* __restrict__ x,
                          const float* __restrict__ gamma, float* __restrict__ out) {
    int b = blockIdx.x;
    int n = b / CCH, o = b % CCH;
    int t = threadIdx.x;
    int wv = t >> 6, ln = t & 63;
    __shared__ float pr[4];

    const float* pw  = proj_w + (size_t)o * CCH;
    const float* ovr = ov + n * CCH;
    float acc = pw[t] * ovr[t] + pw[t + 256] * ovr[t + 256];
    if (t < 64) acc += pw[t + 512] * ovr[t + 512];
    #pragma unroll
    for (int off = 32; off >= 1; off >>= 1)
        acc += __shfl_xor(acc, off, 64);
    if (ln == 0) pr[wv] = acc;
    __syncthreads();
    float base = gamma[0] * ((pr[0] + pr[1] + pr[2] + pr[3]) + proj_b[o]);

    const float4* x4 = (const float4*)(x + ((size_t)n * CCH + o) * HW);
    float4* o4 = (float4*)(out + ((size_t)n * CCH + o) * HW);
    #pragma unroll
    for (int j = 0; j < 4; ++j) {
        int idx = t + 256 * j;           // 1024 float4 per row
        float4 v = x4[idx];
        v.x += base; v.y += base; v.z += base; v.w += base;
        o4[idx] = v;
    }
}

extern "C" void kernel_launch(void* const* d_in, const int* in_sizes, int n_in,
                              void* d_out, int out_size, void* d_ws, size_t ws_size,
                              hipStream_t stream) {
    const float* x         = (const float*)d_in[0];
    const float* key_w     = (const float*)d_in[1];
    // d_in[2] offset_w, d_in[3] dconv_w, d_in[8] appr_bias_q: dead path (a cancels in softmax)
    const float* value_w   = (const float*)d_in[4];
    const float* proj_w    = (const float*)d_in[5];
    const float* proj_b    = (const float*)d_in[6];
    const float* appr_bias = (const float*)d_in[7];
    const float* gamma     = (const float*)d_in[9];
    float* out = (float*)d_out;

    float* ws    = (float*)d_ws;
    float* bpart = ws + WS_BPART;
    float* wx    = ws + WS_WX;
    float* ov    = ws + WS_OV;

    k_bpart  <<<dim3(4, 2, CHN), 256, 0, stream>>>(x, key_w, appr_bias, bpart);
    k_swx    <<<dim3(144, 2), 256, 0, stream>>>(x, bpart, wx);
    k_ov     <<<288, 256, 0, stream>>>(value_w, wx, ov);
    k_pofinal<<<1152, 256, 0, stream>>>(proj_w, proj_b, ov, x, gamma, out);
}